// Round 1
// baseline (1433.318 us; speedup 1.0000x reference)
//
#include <hip/hip_runtime.h>
#include <hip/hip_bf16.h>

// Problem constants
#define Bn 16
#define Sn 16
#define Ln 64
#define En 512
#define Hn 512
#define Nn 512   // B*2*S packed batch
#define G4 2048  // 4*H

typedef __bf16 bf16x8 __attribute__((ext_vector_type(8)));
typedef float f32x4 __attribute__((ext_vector_type(4)));
typedef unsigned short u16x8 __attribute__((ext_vector_type(8)));

__device__ __forceinline__ unsigned short f2bf(float f) {
    union { float f; unsigned u; } v; v.f = f;
    unsigned r = v.u + 0x7FFFu + ((v.u >> 16) & 1u);   // RNE
    return (unsigned short)(r >> 16);
}
__device__ __forceinline__ float bf2f(unsigned short u) {
    union { unsigned u; float f; } v; v.u = ((unsigned)u) << 16;
    return v.f;
}
__device__ __forceinline__ float sigmf(float x) {
    return 1.0f / (1.0f + __expf(-x));
}

// ---------------------------------------------------------------------------
// Prep: convert weights to bf16, bias sum, zero h0 (bf16) and c0 (fp32)
// ---------------------------------------------------------------------------
#define WIH_ELEMS (G4 * En)          // 1048576
#define WHH_ELEMS (G4 * Hn)          // 1048576
#define HS_ELEMS  (Nn * Hn)          // 262144
#define PREP_TOTAL (WIH_ELEMS + WHH_ELEMS + G4 + HS_ELEMS + HS_ELEMS)

__global__ __launch_bounds__(256) void prep_kernel(
    const float* __restrict__ Wih_f, const float* __restrict__ Whh_f,
    const float* __restrict__ bih, const float* __restrict__ bhh,
    unsigned short* __restrict__ Wih, unsigned short* __restrict__ Whh,
    float* __restrict__ bsum, unsigned short* __restrict__ h0,
    float* __restrict__ c0) {
    int i = blockIdx.x * 256 + threadIdx.x;
    if (i < WIH_ELEMS) {
        Wih[i] = f2bf(Wih_f[i]);
    } else if (i < WIH_ELEMS + WHH_ELEMS) {
        int j = i - WIH_ELEMS;
        Whh[j] = f2bf(Whh_f[j]);
    } else if (i < WIH_ELEMS + WHH_ELEMS + G4) {
        int j = i - (WIH_ELEMS + WHH_ELEMS);
        bsum[j] = bih[j] + bhh[j];
    } else if (i < WIH_ELEMS + WHH_ELEMS + G4 + HS_ELEMS) {
        int j = i - (WIH_ELEMS + WHH_ELEMS + G4);
        h0[j] = 0;
    } else if (i < PREP_TOTAL) {
        int j = i - (WIH_ELEMS + WHH_ELEMS + G4 + HS_ELEMS);
        c0[j] = 0.0f;
    }
}

// ---------------------------------------------------------------------------
// One LSTM time step, fused GEMM + cell.
// Grid: 256 WGs = 8 n-tiles (64 rows) x 32 u-tiles (16 hidden units).
// Each WG computes gates[64 x (4 gates x 16 u)] with K = E + H = 1024,
// then the cell update for its [64 x 16] tile. h double-buffered (bf16),
// c single-buffered fp32 (tile-exclusive RMW).
// ---------------------------------------------------------------------------
__global__ __launch_bounds__(256) void lstm_step(
    const float* __restrict__ xf, const float* __restrict__ xa,
    const unsigned short* __restrict__ Wih, const unsigned short* __restrict__ Whh,
    const float* __restrict__ bsum,
    const unsigned short* __restrict__ h_in, unsigned short* __restrict__ h_out,
    float* __restrict__ c, int t) {
    __shared__ __align__(16) unsigned short As[64 * 32];  // A: [row][k] 4KB
    __shared__ __align__(16) unsigned short Bs[64 * 32];  // B^T: [gatecol][k] 4KB

    const int tid = threadIdx.x;
    const int wg = blockIdx.x;
    const int n0 = (wg >> 5) * 64;   // n-tile base
    const int u0 = (wg & 31) * 16;   // hidden-unit tile base

    // staging roles
    const int srow = tid >> 2;       // 0..63 (A row / B gate-col)
    const int seg  = tid & 3;        // 8 elems each

    // x source row pointer for A staging
    const int n_st = n0 + srow;
    const int bb = n_st >> 5, rr = n_st & 31;
    const float* xsrc = (rr < Sn)
        ? xf + ((size_t)(bb * Sn + rr) * Ln + t) * En
        : xa + ((size_t)(bb * Sn + (rr - Sn)) * Ln + t) * En;

    // B staging: gate-col -> W row
    const int bcol = srow;
    const int bgate = bcol >> 4, bu = bcol & 15;
    const size_t wrow = (size_t)(bgate * Hn + u0 + bu) * 512;

    // compute roles
    const int wave = tid >> 6;
    const int lane = tid & 63;
    const int l15 = lane & 15;
    const int kb = lane >> 4;
    const int arow_lds = (wave * 16 + l15) * 32 + kb * 8;

    f32x4 acc[4];
#pragma unroll
    for (int f = 0; f < 4; ++f) acc[f] = (f32x4){0.f, 0.f, 0.f, 0.f};

    for (int kk = 0; kk < 32; ++kk) {
        if (kk) __syncthreads();
        const int kbase = kk * 32;
        // ---- stage A
        if (kk < 16) {
            const float4* s4 = (const float4*)(xsrc + kbase + seg * 8);
            float4 v0 = s4[0], v1 = s4[1];
            u16x8 w;
            w[0] = f2bf(v0.x); w[1] = f2bf(v0.y); w[2] = f2bf(v0.z); w[3] = f2bf(v0.w);
            w[4] = f2bf(v1.x); w[5] = f2bf(v1.y); w[6] = f2bf(v1.z); w[7] = f2bf(v1.w);
            *(u16x8*)&As[srow * 32 + seg * 8] = w;
        } else {
            const int kh = kbase - 512;
            *(u16x8*)&As[srow * 32 + seg * 8] =
                *(const u16x8*)&h_in[(size_t)n_st * Hn + kh + seg * 8];
        }
        // ---- stage B (W rows are contiguous in k)
        {
            const unsigned short* W = (kk < 16) ? Wih : Whh;
            const int ksrc = (kk < 16) ? kbase : kbase - 512;
            *(u16x8*)&Bs[bcol * 32 + seg * 8] =
                *(const u16x8*)&W[wrow + ksrc + seg * 8];
        }
        __syncthreads();
        // ---- MFMA
        bf16x8 a = *(const bf16x8*)&As[arow_lds];
#pragma unroll
        for (int f = 0; f < 4; ++f) {
            bf16x8 b = *(const bf16x8*)&Bs[(f * 16 + l15) * 32 + kb * 8];
            acc[f] = __builtin_amdgcn_mfma_f32_16x16x32_bf16(a, b, acc[f], 0, 0, 0);
        }
    }

    // ---- epilogue: lane-local LSTM cell for 4 rows x 1 col
    const int ucol = u0 + l15;
    const float bi = bsum[ucol];
    const float bf = bsum[512 + ucol];
    const float bg = bsum[1024 + ucol];
    const float bo = bsum[1536 + ucol];
#pragma unroll
    for (int r = 0; r < 4; ++r) {
        const int n = n0 + wave * 16 + kb * 4 + r;
        const size_t idx = (size_t)n * Hn + ucol;
        float ip = acc[0][r] + bi;
        float fp = acc[1][r] + bf;
        float gp = acc[2][r] + bg;
        float op = acc[3][r] + bo;
        float ig = sigmf(ip);
        float fg = sigmf(fp);
        float gg = tanhf(gp);
        float og = sigmf(op);
        float cn = fg * c[idx] + ig * gg;
        c[idx] = cn;
        h_out[idx] = f2bf(og * tanhf(cn));
    }
}

// ---------------------------------------------------------------------------
// Head: mean/max pool over S, FC1 (2048->256), FC2 (256->1), sigmoid.
// One block per batch element.
// ---------------------------------------------------------------------------
__global__ __launch_bounds__(256) void head_kernel(
    const unsigned short* __restrict__ hfin,
    const float* __restrict__ fc1w, const float* __restrict__ fc1b,
    const float* __restrict__ fc2w, const float* __restrict__ fc2b,
    float* __restrict__ out) {
    __shared__ float feat[2048];
    __shared__ float partial[256];
    const int b = blockIdx.x, tid = threadIdx.x;

    for (int p = tid; p < 2 * Hn; p += 256) {
        const int side = p >> 9, u = p & 511;
        float s = 0.0f, m = -1e30f;
#pragma unroll
        for (int ss = 0; ss < Sn; ++ss) {
            float v = bf2f(hfin[(size_t)(b * 32 + side * 16 + ss) * Hn + u]);
            s += v;
            m = fmaxf(m, v);
        }
        feat[side * 1024 + u] = s * (1.0f / 16.0f);
        feat[side * 1024 + 512 + u] = m;
    }
    __syncthreads();

    const int o = tid;
    float z = fc1b[o];
    const float* wrow = fc1w + (size_t)o * 2048;
    for (int k = 0; k < 2048; k += 4) {
        z += feat[k] * wrow[k] + feat[k + 1] * wrow[k + 1] +
             feat[k + 2] * wrow[k + 2] + feat[k + 3] * wrow[k + 3];
    }
    partial[o] = z * fc2w[o];
    __syncthreads();
    if (tid == 0) {
        float y = fc2b[0];
        for (int k = 0; k < 256; ++k) y += partial[k];
        out[b] = sigmf(y);
    }
}

// ---------------------------------------------------------------------------
extern "C" void kernel_launch(void* const* d_in, const int* in_sizes, int n_in,
                              void* d_out, int out_size, void* d_ws, size_t ws_size,
                              hipStream_t stream) {
    const float* xf    = (const float*)d_in[0];
    const float* xa    = (const float*)d_in[1];
    const float* Wih_f = (const float*)d_in[2];
    const float* Whh_f = (const float*)d_in[3];
    const float* bih   = (const float*)d_in[4];
    const float* bhh   = (const float*)d_in[5];
    const float* fc1w  = (const float*)d_in[6];
    const float* fc1b  = (const float*)d_in[7];
    const float* fc2w  = (const float*)d_in[8];
    const float* fc2b  = (const float*)d_in[9];
    float* out = (float*)d_out;

    char* ws = (char*)d_ws;
    unsigned short* Wih  = (unsigned short*)(ws);                    // 2 MB
    unsigned short* Whh  = (unsigned short*)(ws + 2097152);          // 2 MB
    float*          bsum = (float*)(ws + 4194304);                   // 8 KB
    unsigned short* hbuf0 = (unsigned short*)(ws + 4202496);         // 512 KB
    unsigned short* hbuf1 = (unsigned short*)(ws + 4726784);         // 512 KB
    float*          cbuf  = (float*)(ws + 5251072);                  // 1 MB
    // total 6,299,648 bytes

    prep_kernel<<<dim3(PREP_TOTAL / 256), dim3(256), 0, stream>>>(
        Wih_f, Whh_f, bih, bhh, Wih, Whh, bsum, hbuf0, cbuf);

    for (int t = 0; t < Ln; ++t) {
        const unsigned short* hin = (t & 1) ? hbuf1 : hbuf0;
        unsigned short* hout      = (t & 1) ? hbuf0 : hbuf1;
        lstm_step<<<dim3(256), dim3(256), 0, stream>>>(
            xf, xa, Wih, Whh, bsum, hin, hout, cbuf, t);
    }
    // t=63 wrote hbuf0
    head_kernel<<<dim3(Bn), dim3(256), 0, stream>>>(
        hbuf0, fc1w, fc1b, fc2w, fc2b, out);
}

// Round 2
// 620.035 us; speedup vs baseline: 2.3117x; 2.3117x over previous
//
#include <hip/hip_runtime.h>
#include <hip/hip_bf16.h>

// Problem constants
#define Bn 16
#define Sn 16
#define Ln 64
#define En 512
#define Hn 512
#define Nn 512   // B*2*S packed batch
#define G4 2048  // 4*H

typedef __bf16 bf16x8 __attribute__((ext_vector_type(8)));
typedef float f32x4 __attribute__((ext_vector_type(4)));
typedef unsigned short u16x8 __attribute__((ext_vector_type(8)));

__device__ __forceinline__ unsigned short f2bf(float f) {
    union { float f; unsigned u; } v; v.f = f;
    unsigned r = v.u + 0x7FFFu + ((v.u >> 16) & 1u);   // RNE
    return (unsigned short)(r >> 16);
}
__device__ __forceinline__ float bf2f(unsigned short u) {
    union { unsigned u; float f; } v; v.u = ((unsigned)u) << 16;
    return v.f;
}
__device__ __forceinline__ float sigmf(float x) {
    return 1.0f / (1.0f + __expf(-x));
}
__device__ __forceinline__ float tanh_fast(float x) {
    x = fminf(fmaxf(x, -15.0f), 15.0f);
    float e = __expf(2.0f * x);
    return (e - 1.0f) / (e + 1.0f);
}

// ---------------------------------------------------------------------------
// Prep: convert weights to bf16, bias sum, zero h0 (bf16) and c0 (fp32)
// ---------------------------------------------------------------------------
#define WIH_ELEMS (G4 * En)          // 1048576
#define WHH_ELEMS (G4 * Hn)          // 1048576
#define HS_ELEMS  (Nn * Hn)          // 262144
#define PREP_TOTAL (WIH_ELEMS + WHH_ELEMS + G4 + HS_ELEMS + HS_ELEMS)

__global__ __launch_bounds__(256) void prep_kernel(
    const float* __restrict__ Wih_f, const float* __restrict__ Whh_f,
    const float* __restrict__ bih, const float* __restrict__ bhh,
    unsigned short* __restrict__ Wih, unsigned short* __restrict__ Whh,
    float* __restrict__ bsum, unsigned short* __restrict__ h0,
    float* __restrict__ c0) {
    int i = blockIdx.x * 256 + threadIdx.x;
    if (i < WIH_ELEMS) {
        Wih[i] = f2bf(Wih_f[i]);
    } else if (i < WIH_ELEMS + WHH_ELEMS) {
        int j = i - WIH_ELEMS;
        Whh[j] = f2bf(Whh_f[j]);
    } else if (i < WIH_ELEMS + WHH_ELEMS + G4) {
        int j = i - (WIH_ELEMS + WHH_ELEMS);
        bsum[j] = bih[j] + bhh[j];
    } else if (i < WIH_ELEMS + WHH_ELEMS + G4 + HS_ELEMS) {
        int j = i - (WIH_ELEMS + WHH_ELEMS + G4);
        h0[j] = 0;
    } else if (i < PREP_TOTAL) {
        int j = i - (WIH_ELEMS + WHH_ELEMS + G4 + HS_ELEMS);
        c0[j] = 0.0f;
    }
}

// ---------------------------------------------------------------------------
// One LSTM time step.
// Grid 256 WGs x 512 threads. WG tile: 64 n-rows x 64 gate-cols (16 units).
// Wave-group 0 (tid<256): x @ W_ih^T (K=512). Wave-group 1: h @ W_hh^T (K=512).
// BK=64, double-buffered LDS + register prefetch, XOR-swizzled tiles.
// Group1 acc -> LDS -> group0 adds, applies cell, stores h (bf16) + c (f32).
// ---------------------------------------------------------------------------
__global__ __launch_bounds__(512) void lstm_step(
    const float* __restrict__ xf, const float* __restrict__ xa,
    const unsigned short* __restrict__ Wih, const unsigned short* __restrict__ Whh,
    const float* __restrict__ bsum,
    const unsigned short* __restrict__ h_in, unsigned short* __restrict__ h_out,
    float* __restrict__ c, int t) {
    // layout: per group 32KB: {buf0: As 8K, Bs 8K}, {buf1: As 8K, Bs 8K}
    __shared__ __align__(16) char smem[65536];

    const int tid = threadIdx.x;
    const int grp = tid >> 8;            // 0 or 1
    const int gtid = tid & 255;
    const int gwave = gtid >> 6;         // 0..3
    const int lane = tid & 63;
    const int l15 = lane & 15;
    const int kb = lane >> 4;            // 0..3

    const int wg = blockIdx.x;
    const int n0 = (wg >> 5) * 64;       // n-tile base
    const int u0 = (wg & 31) * 16;       // hidden-unit tile base

    char* gbase = smem + grp * 32768;

    // staging roles: 4 threads per row, 16 k-elems each
    const int r = gtid >> 2;             // 0..63
    const int seg = gtid & 3;

    const int n_st = n0 + r;
    const int bb = n_st >> 5, rr = n_st & 31;
    const float* xsrc = (rr < Sn)
        ? xf + ((size_t)(bb * Sn + rr) * Ln + t) * En
        : xa + ((size_t)(bb * Sn + (rr - Sn)) * Ln + t) * En;
    const unsigned short* hsrc = h_in + (size_t)n_st * Hn;

    const int bgate = r >> 4, bu = r & 15;
    const unsigned short* wsrc = ((grp == 0) ? Wih : Whh)
        + (size_t)(bgate * Hn + u0 + bu) * 512;

    // swizzled write offsets: row r, chunks 2*seg and 2*seg+1
    const int swz = r & 7;
    const int aofs0 = r * 128 + (((2 * seg) ^ swz) * 16);
    const int aofs1 = r * 128 + (((2 * seg + 1) ^ swz) * 16);

    f32x4 acc[4];
#pragma unroll
    for (int f = 0; f < 4; ++f) acc[f] = (f32x4){0.f, 0.f, 0.f, 0.f};

    // prefetch registers (raw; cvt deferred to write time for grp0)
    float4 xv0, xv1, xv2, xv3;
    u16x8 hv0, hv1, wv0, wv1;

#define STAGE_LOAD(IT) do {                                             \
        const int ko = (IT) * 64 + seg * 16;                            \
        if (grp == 0) {                                                 \
            const float4* s4 = (const float4*)(xsrc + ko);              \
            xv0 = s4[0]; xv1 = s4[1]; xv2 = s4[2]; xv3 = s4[3];         \
        } else {                                                        \
            hv0 = *(const u16x8*)(hsrc + ko);                           \
            hv1 = *(const u16x8*)(hsrc + ko + 8);                       \
        }                                                               \
        wv0 = *(const u16x8*)(wsrc + ko);                               \
        wv1 = *(const u16x8*)(wsrc + ko + 8);                           \
    } while (0)

    STAGE_LOAD(0);

#pragma unroll
    for (int it = 0; it < 8; ++it) {
        char* buf = gbase + (it & 1) * 16384;
        // ---- write current tile to LDS (cvt for grp0 here)
        u16x8 a0, a1;
        if (grp == 0) {
            u16x8 w;
            w[0] = f2bf(xv0.x); w[1] = f2bf(xv0.y); w[2] = f2bf(xv0.z); w[3] = f2bf(xv0.w);
            w[4] = f2bf(xv1.x); w[5] = f2bf(xv1.y); w[6] = f2bf(xv1.z); w[7] = f2bf(xv1.w);
            a0 = w;
            w[0] = f2bf(xv2.x); w[1] = f2bf(xv2.y); w[2] = f2bf(xv2.z); w[3] = f2bf(xv2.w);
            w[4] = f2bf(xv3.x); w[5] = f2bf(xv3.y); w[6] = f2bf(xv3.z); w[7] = f2bf(xv3.w);
            a1 = w;
        } else {
            a0 = hv0; a1 = hv1;
        }
        *(u16x8*)(buf + aofs0) = a0;
        *(u16x8*)(buf + aofs1) = a1;
        *(u16x8*)(buf + 8192 + aofs0) = wv0;
        *(u16x8*)(buf + 8192 + aofs1) = wv1;
        // ---- issue next-tile loads (latency hides under barrier+MFMA)
        if (it < 7) STAGE_LOAD(it + 1);
        __syncthreads();
        // ---- compute from buf
        const char* As = buf;
        const char* Bs = buf + 8192;
        const int arow = gwave * 16 + l15;
        const int aswz = arow & 7;
#pragma unroll
        for (int ks = 0; ks < 2; ++ks) {
            bf16x8 a = *(const bf16x8*)(As + arow * 128 + (((ks * 4 + kb) ^ aswz) * 16));
#pragma unroll
            for (int f = 0; f < 4; ++f) {
                const int brow = f * 16 + l15;
                bf16x8 b = *(const bf16x8*)(Bs + brow * 128 + (((ks * 4 + kb) ^ (brow & 7)) * 16));
                acc[f] = __builtin_amdgcn_mfma_f32_16x16x32_bf16(a, b, acc[f], 0, 0, 0);
            }
        }
        // single barrier per iter is sufficient with 2 buffers
    }
#undef STAGE_LOAD

    // ---- k-split reduce: group1 -> LDS, group0 adds + cell epilogue
    __syncthreads();
    float* accx = (float*)smem;          // [4][64 rows][16 cols] = 16KB
    if (grp == 1) {
#pragma unroll
        for (int f = 0; f < 4; ++f)
#pragma unroll
            for (int q = 0; q < 4; ++q)
                accx[f * 1024 + (gwave * 16 + kb * 4 + q) * 16 + l15] = acc[f][q];
    }
    __syncthreads();
    if (grp == 0) {
        const int ucol = u0 + l15;
        const float bi = bsum[ucol];
        const float bf_ = bsum[512 + ucol];
        const float bg = bsum[1024 + ucol];
        const float bo = bsum[1536 + ucol];
#pragma unroll
        for (int q = 0; q < 4; ++q) {
            const int row = gwave * 16 + kb * 4 + q;
            const int n = n0 + row;
            const size_t idx = (size_t)n * Hn + ucol;
            float ip = acc[0][q] + accx[0 * 1024 + row * 16 + l15] + bi;
            float fp = acc[1][q] + accx[1 * 1024 + row * 16 + l15] + bf_;
            float gp = acc[2][q] + accx[2 * 1024 + row * 16 + l15] + bg;
            float op = acc[3][q] + accx[3 * 1024 + row * 16 + l15] + bo;
            float ig = sigmf(ip);
            float fg = sigmf(fp);
            float gg = tanh_fast(gp);
            float og = sigmf(op);
            float cn = fg * c[idx] + ig * gg;
            c[idx] = cn;
            h_out[idx] = f2bf(og * tanh_fast(cn));
        }
    }
}

// ---------------------------------------------------------------------------
// Head, split into 3 parallel micro-kernels.
// ---------------------------------------------------------------------------
// pool: grid 32 = (b, side); mean/max over S=16 -> feat[b][2048]
// feat order: [for_mean | for_max | against_mean | against_max]
__global__ __launch_bounds__(256) void pool_kernel(
    const unsigned short* __restrict__ hfin, float* __restrict__ feat) {
    const int blk = blockIdx.x;
    const int b = blk >> 1, side = blk & 1;
    const int tid = threadIdx.x;
    for (int u = tid; u < Hn; u += 256) {
        float s = 0.0f, m = -1e30f;
#pragma unroll
        for (int ss = 0; ss < Sn; ++ss) {
            float v = bf2f(hfin[(size_t)(b * 32 + side * 16 + ss) * Hn + u]);
            s += v;
            m = fmaxf(m, v);
        }
        feat[b * 2048 + side * 1024 + u] = s * (1.0f / 16.0f);
        feat[b * 2048 + side * 1024 + 512 + u] = m;
    }
}

// fc1: grid 256 = (b 16, oc 16); block computes 16 outputs for one b.
__global__ __launch_bounds__(256) void fc1_kernel(
    const float* __restrict__ feat, const float* __restrict__ fc1w,
    const float* __restrict__ fc1b, float* __restrict__ z1) {
    __shared__ float fs[2048];
    __shared__ float red[256];
    const int b = blockIdx.x >> 4, oc = blockIdx.x & 15;
    const int tid = threadIdx.x;
    for (int k = tid; k < 2048; k += 256) fs[k] = feat[b * 2048 + k];
    __syncthreads();
    const int o = oc * 16 + (tid & 15);
    const int ks = (tid >> 4) * 128;
    const float4* w4 = (const float4*)(fc1w + (size_t)o * 2048 + ks);
    const float* fr = fs + ks;
    float p = 0.0f;
#pragma unroll 8
    for (int k = 0; k < 32; ++k) {
        float4 w = w4[k];
        p += fr[k * 4] * w.x + fr[k * 4 + 1] * w.y +
             fr[k * 4 + 2] * w.z + fr[k * 4 + 3] * w.w;
    }
    red[(tid & 15) * 16 + (tid >> 4)] = p;
    __syncthreads();
    if (tid < 16) {
        float z = fc1b[oc * 16 + tid];
#pragma unroll
        for (int j = 0; j < 16; ++j) z += red[tid * 16 + j];
        z1[b * 256 + oc * 16 + tid] = z;
    }
}

// fc2: grid 16; dot(z1[b], fc2w) + fc2b -> sigmoid
__global__ __launch_bounds__(256) void fc2_kernel(
    const float* __restrict__ z1, const float* __restrict__ fc2w,
    const float* __restrict__ fc2b, float* __restrict__ out) {
    __shared__ float sh[256];
    const int b = blockIdx.x, tid = threadIdx.x;
    sh[tid] = z1[b * 256 + tid] * fc2w[tid];
    __syncthreads();
    for (int s = 128; s > 0; s >>= 1) {
        if (tid < s) sh[tid] += sh[tid + s];
        __syncthreads();
    }
    if (tid == 0) out[b] = sigmf(sh[0] + fc2b[0]);
}

// ---------------------------------------------------------------------------
extern "C" void kernel_launch(void* const* d_in, const int* in_sizes, int n_in,
                              void* d_out, int out_size, void* d_ws, size_t ws_size,
                              hipStream_t stream) {
    const float* xf    = (const float*)d_in[0];
    const float* xa    = (const float*)d_in[1];
    const float* Wih_f = (const float*)d_in[2];
    const float* Whh_f = (const float*)d_in[3];
    const float* bih   = (const float*)d_in[4];
    const float* bhh   = (const float*)d_in[5];
    const float* fc1w  = (const float*)d_in[6];
    const float* fc1b  = (const float*)d_in[7];
    const float* fc2w  = (const float*)d_in[8];
    const float* fc2b  = (const float*)d_in[9];
    float* out = (float*)d_out;

    char* ws = (char*)d_ws;
    unsigned short* Wih   = (unsigned short*)(ws);                   // 2 MB
    unsigned short* Whh   = (unsigned short*)(ws + 2097152);         // 2 MB
    float*          bsum  = (float*)(ws + 4194304);                  // 8 KB
    unsigned short* hbuf0 = (unsigned short*)(ws + 4202496);         // 512 KB
    unsigned short* hbuf1 = (unsigned short*)(ws + 4726784);         // 512 KB
    float*          cbuf  = (float*)(ws + 5251072);                  // 1 MB
    float*          feat  = (float*)(ws + 6299648);                  // 128 KB
    float*          z1    = (float*)(ws + 6430720);                  // 16 KB
    // total 6,446,080 bytes + z1 16K = 6,447,104

    prep_kernel<<<dim3(PREP_TOTAL / 256), dim3(256), 0, stream>>>(
        Wih_f, Whh_f, bih, bhh, Wih, Whh, bsum, hbuf0, cbuf);

    for (int t = 0; t < Ln; ++t) {
        const unsigned short* hin = (t & 1) ? hbuf1 : hbuf0;
        unsigned short* hout      = (t & 1) ? hbuf0 : hbuf1;
        lstm_step<<<dim3(256), dim3(512), 0, stream>>>(
            xf, xa, Wih, Whh, bsum, hin, hout, cbuf, t);
    }
    // t=63 wrote hbuf0
    pool_kernel<<<dim3(32), dim3(256), 0, stream>>>(hbuf0, feat);
    fc1_kernel<<<dim3(256), dim3(256), 0, stream>>>(feat, fc1w, fc1b, z1);
    fc2_kernel<<<dim3(16), dim3(256), 0, stream>>>(z1, fc2w, fc2b, out);
}